// Round 1
// baseline (311.884 us; speedup 1.0000x reference)
//
#include <hip/hip_runtime.h>
#include <cstdint>
#include <cstddef>

typedef unsigned short u16;
typedef __attribute__((ext_vector_type(4))) float f32x4;
typedef __attribute__((ext_vector_type(4))) short s16x4;
typedef __attribute__((ext_vector_type(8))) short s16x8;
typedef __attribute__((ext_vector_type(8))) __bf16 bf16x8;

#define DEV __device__ __forceinline__

constexpr int BATCH = 2;
constexpr int SEQ   = 2048;
constexpr int DM    = 1024;   // model dim
constexpr int NH    = 16;     // heads
constexpr int HD    = 64;     // head dim (K and V)
constexpr int NTOK  = BATCH * SEQ;  // 4096

DEV u16 f2b(float x) {                 // fp32 -> bf16 round-to-nearest-even
  unsigned u = __builtin_bit_cast(unsigned, x);
  u = u + 0x7FFFu + ((u >> 16) & 1u);
  return (u16)(u >> 16);
}

// MFMA 16x16x32 A/B fragment: elems 0..3 at k = 4*(lane>>4)+i, elems 4..7 at k+16
DEV bf16x8 ldfrag(const u16* p) {
  union { s16x4 h[2]; bf16x8 v; } u;
  u.h[0] = *(const s16x4*)p;
  u.h[1] = *(const s16x4*)(p + 16);
  return u.v;
}

// ---------------- convert x: fp32 -> bf16 ----------------
__global__ void k_cvt(const float* __restrict__ x, u16* __restrict__ y) {
  int i = (blockIdx.x * 256 + threadIdx.x) * 4;
  float4 v = *(const float4*)(x + i);
  union { u16 a[4]; s16x4 s; } o;
  o.a[0] = f2b(v.x); o.a[1] = f2b(v.y); o.a[2] = f2b(v.z); o.a[3] = f2b(v.w);
  *(s16x4*)(y + i) = o.s;
}

// ---------------- transpose+convert weights (1024x1024 fp32 -> bf16 [out][in]) ----------------
__global__ void k_wtrans(const float* __restrict__ w0, const float* __restrict__ w1,
                         const float* __restrict__ w2, const float* __restrict__ w3,
                         u16* __restrict__ t0, u16* __restrict__ t1,
                         u16* __restrict__ t2, u16* __restrict__ t3) {
  const float* w; u16* t;
  switch (blockIdx.z) {
    case 0: w = w0; t = t0; break;
    case 1: w = w1; t = t1; break;
    case 2: w = w2; t = t2; break;
    default: w = w3; t = t3; break;
  }
  __shared__ float tile[32][33];
  int tx = threadIdx.x & 31, ty = threadIdx.x >> 5;  // 32 x 8
  int r0 = blockIdx.y * 32, c0 = blockIdx.x * 32;
#pragma unroll
  for (int i = 0; i < 4; i++)
    tile[ty + 8 * i][tx] = w[(size_t)(r0 + ty + 8 * i) * DM + c0 + tx];
  __syncthreads();
#pragma unroll
  for (int i = 0; i < 4; i++)
    t[(size_t)(c0 + ty + 8 * i) * DM + r0 + tx] = f2b(tile[tx][ty + 8 * i]);
}

// ---------------- GEMM: C[M,N] = A[M,K] * BT[N,K]^T  (bf16 MFMA) ----------------
// MODE 0: bf16 out, blockIdx.z selects (BT, C) among 3.  MODE 1: fp32 out + bias.
template <int MODE>
__global__ __launch_bounds__(256) void k_gemm(
    const u16* __restrict__ A,
    const u16* __restrict__ B0, const u16* __restrict__ B1, const u16* __restrict__ B2,
    u16* __restrict__ C0, u16* __restrict__ C1, u16* __restrict__ C2,
    float* __restrict__ Cf, const float* __restrict__ bias) {
  constexpr int N = 1024, K = 1024, BM = 128, BN = 128, BK = 64;
  const u16* Bt = B0;
  u16* Cb = C0;
  if (MODE == 0) {
    int z = blockIdx.z;
    Bt = (z == 0) ? B0 : (z == 1) ? B1 : B2;
    Cb = (z == 0) ? C0 : (z == 1) ? C1 : C2;
  }
  const int m0 = blockIdx.y * BM, n0 = blockIdx.x * BN;
  __shared__ u16 As[BM][BK + 8];
  __shared__ u16 Bs[BN][BK + 8];
  const int t = threadIdx.x;
  const int wid = t >> 6, lane = t & 63, lr = lane & 15, lg = lane >> 4;
  const int wm = wid >> 1, wn = wid & 1;

  const f32x4 z4 = {0.f, 0.f, 0.f, 0.f};
  f32x4 acc[4][4];
#pragma unroll
  for (int a = 0; a < 4; a++)
#pragma unroll
    for (int b = 0; b < 4; b++) acc[a][b] = z4;

  for (int kt = 0; kt < K; kt += BK) {
#pragma unroll
    for (int p = 0; p < 4; p++) {
      int c = p * 256 + t;
      int r = c >> 3, off = (c & 7) * 8;
      *(s16x8*)&As[r][off] = *(const s16x8*)&A[(size_t)(m0 + r) * K + kt + off];
      *(s16x8*)&Bs[r][off] = *(const s16x8*)&Bt[(size_t)(n0 + r) * K + kt + off];
    }
    __syncthreads();
#pragma unroll
    for (int kk = 0; kk < 2; kk++) {
      const int kb = kk * 32 + 4 * lg;
      bf16x8 af[4], bfr[4];
#pragma unroll
      for (int a = 0; a < 4; a++) af[a] = ldfrag(&As[wm * 64 + a * 16 + lr][kb]);
#pragma unroll
      for (int b = 0; b < 4; b++) bfr[b] = ldfrag(&Bs[wn * 64 + b * 16 + lr][kb]);
#pragma unroll
      for (int a = 0; a < 4; a++)
#pragma unroll
        for (int b = 0; b < 4; b++)
          acc[a][b] = __builtin_amdgcn_mfma_f32_16x16x32_bf16(af[a], bfr[b], acc[a][b], 0, 0, 0);
    }
    __syncthreads();
  }
  // epilogue: C layout col=lane&15, row=(lane>>4)*4+reg
#pragma unroll
  for (int a = 0; a < 4; a++) {
#pragma unroll
    for (int b = 0; b < 4; b++) {
      const int c = n0 + wn * 64 + b * 16 + lr;
      float bb = (MODE == 1) ? bias[c] : 0.f;
#pragma unroll
      for (int j = 0; j < 4; j++) {
        const int r = m0 + wm * 64 + a * 16 + lg * 4 + j;
        if (MODE == 0)
          Cb[(size_t)r * N + c] = f2b(acc[a][b][j]);
        else
          Cf[(size_t)r * N + c] = acc[a][b][j] + bb;
      }
    }
  }
}

// ---------------- V -> Vt  (per (b,h): [S,64] -> [64,S]) ----------------
__global__ void k_vtrans(const u16* __restrict__ V, u16* __restrict__ Vt) {
  const int bh = blockIdx.y, b = bh >> 4, h = bh & 15;
  const int t0 = blockIdx.x * 64;
  __shared__ u16 tile[64][72];
  const int t = threadIdx.x;
#pragma unroll
  for (int p = 0; p < 2; p++) {
    int c = p * 256 + t;
    int row = c >> 3, off = (c & 7) * 8;
    *(s16x8*)&tile[row][off] =
        *(const s16x8*)&V[(size_t)(b * SEQ + t0 + row) * DM + h * HD + off];
  }
  __syncthreads();
#pragma unroll
  for (int p = 0; p < 2; p++) {
    int c = p * 256 + t;
    int vd = c >> 3, off = (c & 7) * 8;
    union { u16 a[8]; s16x8 v; } u;
#pragma unroll
    for (int i = 0; i < 8; i++) u.a[i] = tile[off + i][vd];
    *(s16x8*)&Vt[(size_t)(bh * HD + vd) * SEQ + t0 + off] = u.v;
  }
}

// ---------------- flash attention ----------------
// grid (S/64, B*H), 256 thr = 4 waves; wave w owns q rows [q0+16w, q0+16w+16)
__global__ __launch_bounds__(256) void k_attn(const u16* __restrict__ Q, const u16* __restrict__ K,
                                              const u16* __restrict__ Vt, u16* __restrict__ O) {
  __shared__ u16 KS[64][72];
  __shared__ u16 VS[64][72];   // Vt tile: [vd][key]
  __shared__ u16 PS[4][16][72];
  const int bh = blockIdx.y, b = bh >> 4, h = bh & 15;
  const int q0 = blockIdx.x * 64;
  const int t = threadIdx.x, w = t >> 6, lane = t & 63, lr = lane & 15, lg = lane >> 4;

  const u16* qrow = Q + (size_t)(b * SEQ + q0 + w * 16 + lr) * DM + h * HD;
  const bf16x8 qf0 = ldfrag(qrow + 4 * lg);
  const bf16x8 qf1 = ldfrag(qrow + 32 + 4 * lg);

  float m[4] = {-3e38f, -3e38f, -3e38f, -3e38f};
  float l[4] = {0.f, 0.f, 0.f, 0.f};
  const f32x4 z4 = {0.f, 0.f, 0.f, 0.f};
  f32x4 o[4] = {z4, z4, z4, z4};
  const float sc = 0.125f;  // 1/sqrt(64)

  for (int kv0 = 0; kv0 < SEQ; kv0 += 64) {
#pragma unroll
    for (int p = 0; p < 2; p++) {
      int c = p * 256 + t;
      int row = c >> 3, off = (c & 7) * 8;
      *(s16x8*)&KS[row][off] =
          *(const s16x8*)&K[(size_t)(b * SEQ + kv0 + row) * DM + h * HD + off];
      *(s16x8*)&VS[row][off] =
          *(const s16x8*)&Vt[(size_t)(bh * HD + row) * SEQ + kv0 + off];
    }
    __syncthreads();

    // S = Q K^T : D row = q-local, col = key-local
    f32x4 s[4] = {z4, z4, z4, z4};
#pragma unroll
    for (int kk = 0; kk < 2; kk++) {
      const bf16x8 qf = kk ? qf1 : qf0;
#pragma unroll
      for (int n = 0; n < 4; n++) {
        bf16x8 kf = ldfrag(&KS[n * 16 + lr][kk * 32 + 4 * lg]);
        s[n] = __builtin_amdgcn_mfma_f32_16x16x32_bf16(qf, kf, s[n], 0, 0, 0);
      }
    }

    // online softmax; row r = 4*lg + j lives in the 16 lanes of group lg
    float al[4];
#pragma unroll
    for (int j = 0; j < 4; j++) {
      float v = fmaxf(fmaxf(s[0][j], s[1][j]), fmaxf(s[2][j], s[3][j]));
      v = fmaxf(v, __shfl_xor(v, 1));
      v = fmaxf(v, __shfl_xor(v, 2));
      v = fmaxf(v, __shfl_xor(v, 4));
      v = fmaxf(v, __shfl_xor(v, 8));
      float mn = fmaxf(m[j], v);
      al[j] = __expf((m[j] - mn) * sc);
      m[j] = mn;
    }
#pragma unroll
    for (int j = 0; j < 4; j++) {
      float r = 0.f;
#pragma unroll
      for (int n = 0; n < 4; n++) {
        float p = __expf((s[n][j] - m[j]) * sc);
        s[n][j] = p;
        r += p;
      }
      r += __shfl_xor(r, 1);
      r += __shfl_xor(r, 2);
      r += __shfl_xor(r, 4);
      r += __shfl_xor(r, 8);
      l[j] = l[j] * al[j] + r;
      o[0][j] *= al[j]; o[1][j] *= al[j]; o[2][j] *= al[j]; o[3][j] *= al[j];
    }

    // stage P (per-wave region)
#pragma unroll
    for (int n = 0; n < 4; n++)
#pragma unroll
      for (int j = 0; j < 4; j++)
        PS[w][lg * 4 + j][n * 16 + lr] = f2b(s[n][j]);
    __syncthreads();

    // O += P V : A = P[q][key] (row=lr), B = V[key][vd] via Vt tile (col=lr)
#pragma unroll
    for (int kc = 0; kc < 2; kc++) {
      bf16x8 pf = ldfrag(&PS[w][lr][kc * 32 + 4 * lg]);
#pragma unroll
      for (int v = 0; v < 4; v++) {
        bf16x8 vf = ldfrag(&VS[v * 16 + lr][kc * 32 + 4 * lg]);
        o[v] = __builtin_amdgcn_mfma_f32_16x16x32_bf16(pf, vf, o[v], 0, 0, 0);
      }
    }
    __syncthreads();
  }

#pragma unroll
  for (int j = 0; j < 4; j++) {
    float inv = 1.0f / l[j];
    const int r = b * SEQ + q0 + w * 16 + lg * 4 + j;
#pragma unroll
    for (int v = 0; v < 4; v++)
      O[(size_t)r * DM + h * HD + v * 16 + lr] = f2b(o[v][j] * inv);
  }
}

// ---------------- launch ----------------
extern "C" void kernel_launch(void* const* d_in, const int* in_sizes, int n_in,
                              void* d_out, int out_size, void* d_ws, size_t ws_size,
                              hipStream_t stream) {
  const float* x  = (const float*)d_in[0];
  const float* Wq = (const float*)d_in[1];
  const float* Wk = (const float*)d_in[2];
  const float* Wv = (const float*)d_in[3];
  const float* Wo = (const float*)d_in[4];
  const float* bo = (const float*)d_in[5];
  float* out = (float*)d_out;

  char* ws = (char*)d_ws;
  const size_t MB = 1 << 20;
  u16* xb  = (u16*)(ws + 0 * MB);   // 4096x1024 bf16 (8 MiB)
  u16* WqT = (u16*)(ws + 8 * MB);   // 1024x1024 (2 MiB)
  u16* WkT = (u16*)(ws + 10 * MB);
  u16* WvT = (u16*)(ws + 12 * MB);
  u16* WoT = (u16*)(ws + 14 * MB);
  u16* Qb  = (u16*)(ws + 16 * MB);  // 8 MiB each
  u16* Kb  = (u16*)(ws + 24 * MB);
  u16* Vb  = (u16*)(ws + 32 * MB);
  u16* Vtb = (u16*)(ws + 40 * MB);
  u16* Ob  = (u16*)(ws + 48 * MB);

  k_cvt<<<dim3(NTOK * DM / 1024), 256, 0, stream>>>(x, xb);
  k_wtrans<<<dim3(32, 32, 4), 256, 0, stream>>>(Wq, Wk, Wv, Wo, WqT, WkT, WvT, WoT);
  k_gemm<0><<<dim3(8, 32, 3), 256, 0, stream>>>(xb, WqT, WkT, WvT, Qb, Kb, Vb, nullptr, nullptr);
  k_vtrans<<<dim3(32, 32), 256, 0, stream>>>(Vb, Vtb);
  k_attn<<<dim3(32, 32), 256, 0, stream>>>(Qb, Kb, Vtb, Ob);
  k_gemm<1><<<dim3(8, 32, 1), 256, 0, stream>>>(Ob, WoT, nullptr, nullptr, nullptr, nullptr,
                                                nullptr, out, bo);
}

// Round 3
// 236.616 us; speedup vs baseline: 1.3181x; 1.3181x over previous
//
#include <hip/hip_runtime.h>
#include <cstdint>
#include <cstddef>

typedef unsigned short u16;
typedef __attribute__((ext_vector_type(4))) float f32x4;
typedef __attribute__((ext_vector_type(4))) short s16x4;
typedef __attribute__((ext_vector_type(8))) short s16x8;
typedef __attribute__((ext_vector_type(8))) __bf16 bf16x8;

#define DEV __device__ __forceinline__
#define GLOAD_LDS(src, dst)                                        \
  __builtin_amdgcn_global_load_lds(                                \
      (const __attribute__((address_space(1))) void*)(src),        \
      (__attribute__((address_space(3))) void*)(dst), 16, 0, 0)

constexpr int BATCH = 2;
constexpr int SEQ   = 2048;
constexpr int DM    = 1024;
constexpr int NH    = 16;
constexpr int HD    = 64;
constexpr int NTOK  = BATCH * SEQ;

DEV u16 f2b(float x) {
  unsigned u = __builtin_bit_cast(unsigned, x);
  u = u + 0x7FFFu + ((u >> 16) & 1u);
  return (u16)(u >> 16);
}

DEV bf16x8 ldfrag(const u16* p) {   // linear (global) fragment load: k and k+16
  union { s16x4 h[2]; bf16x8 v; } u;
  u.h[0] = *(const s16x4*)p;
  u.h[1] = *(const s16x4*)(p + 16);
  return u.v;
}

// swizzled LDS fragment load: base row ptr + two XOR'd element offsets
DEV bf16x8 ldfrag2(const u16* rowp, int o1, int o2) {
  union { s16x4 h[2]; bf16x8 v; } u;
  u.h[0] = *(const s16x4*)(rowp + o1);
  u.h[1] = *(const s16x4*)(rowp + o2);
  return u.v;
}

DEV f32x4 vmax4(f32x4 a, f32x4 b) {
  f32x4 r;
#pragma unroll
  for (int j = 0; j < 4; j++) r[j] = fmaxf(a[j], b[j]);
  return r;
}

// ---------------- convert x: fp32 -> bf16 ----------------
__global__ void k_cvt(const float* __restrict__ x, u16* __restrict__ y) {
  int i = (blockIdx.x * 256 + threadIdx.x) * 4;
  float4 v = *(const float4*)(x + i);
  union { u16 a[4]; s16x4 s; } o;
  o.a[0] = f2b(v.x); o.a[1] = f2b(v.y); o.a[2] = f2b(v.z); o.a[3] = f2b(v.w);
  *(s16x4*)(y + i) = o.s;
}

// ---------------- transpose+convert weights ----------------
__global__ void k_wtrans(const float* __restrict__ w0, const float* __restrict__ w1,
                         const float* __restrict__ w2, const float* __restrict__ w3,
                         u16* __restrict__ t0, u16* __restrict__ t1,
                         u16* __restrict__ t2, u16* __restrict__ t3) {
  const float* w; u16* t;
  switch (blockIdx.z) {
    case 0: w = w0; t = t0; break;
    case 1: w = w1; t = t1; break;
    case 2: w = w2; t = t2; break;
    default: w = w3; t = t3; break;
  }
  __shared__ float tile[32][33];
  int tx = threadIdx.x & 31, ty = threadIdx.x >> 5;
  int r0 = blockIdx.y * 32, c0 = blockIdx.x * 32;
#pragma unroll
  for (int i = 0; i < 4; i++)
    tile[ty + 8 * i][tx] = w[(size_t)(r0 + ty + 8 * i) * DM + c0 + tx];
  __syncthreads();
#pragma unroll
  for (int i = 0; i < 4; i++)
    t[(size_t)(c0 + ty + 8 * i) * DM + r0 + tx] = f2b(tile[tx][ty + 8 * i]);
}

// ---------------- GEMM: C[M,N] = A[M,K] * BT[N,K]^T ----------------
template <int MODE>
__global__ __launch_bounds__(256) void k_gemm(
    const u16* __restrict__ A,
    const u16* __restrict__ B0, const u16* __restrict__ B1, const u16* __restrict__ B2,
    u16* __restrict__ C0, u16* __restrict__ C1, u16* __restrict__ C2,
    float* __restrict__ Cf, const float* __restrict__ bias) {
  constexpr int N = 1024, K = 1024, BM = 128, BN = 128, BK = 64;
  const u16* Bt = B0;
  u16* Cb = C0;
  if (MODE == 0) {
    int z = blockIdx.z;
    Bt = (z == 0) ? B0 : (z == 1) ? B1 : B2;
    Cb = (z == 0) ? C0 : (z == 1) ? C1 : C2;
  }
  const int m0 = blockIdx.y * BM, n0 = blockIdx.x * BN;
  __shared__ u16 As[BM][BK];   // linear dest for global_load_lds; data pre-swizzled
  __shared__ u16 Bs[BN][BK];
  const int t = threadIdx.x;
  const int wid = t >> 6, lane = t & 63, lr = lane & 15, lg = lane >> 4;
  const int wm = wid >> 1, wn = wid & 1;
  const int l8 = lane >> 3;
  const int scol = (((lane & 7) ^ l8) << 3);  // pre-swizzled source column (elems)
  const int xsw = (lr & 7) << 3;              // read-side XOR (elems)

  const f32x4 z4 = {0.f, 0.f, 0.f, 0.f};
  f32x4 acc[4][4];
#pragma unroll
  for (int a = 0; a < 4; a++)
#pragma unroll
    for (int b = 0; b < 4; b++) acc[a][b] = z4;

  const u16* Ap = A + (size_t)m0 * K;
  const u16* Bp = Bt + (size_t)n0 * K;

  for (int kt = 0; kt < K; kt += BK) {
#pragma unroll
    for (int s2 = 0; s2 < 4; s2++) {
      const int seg = wid * 4 + s2;
      const int row = seg * 8 + l8;
      GLOAD_LDS(Ap + (size_t)row * K + kt + scol, &As[seg * 8][0]);
      GLOAD_LDS(Bp + (size_t)row * K + kt + scol, &Bs[seg * 8][0]);
    }
    __syncthreads();
#pragma unroll
    for (int kk = 0; kk < 2; kk++) {
      const int e = kk * 32 + 4 * lg;
      const int o1 = e ^ xsw, o2 = (e + 16) ^ xsw;
      bf16x8 af[4], bfr[4];
#pragma unroll
      for (int a = 0; a < 4; a++) af[a] = ldfrag2(&As[wm * 64 + a * 16 + lr][0], o1, o2);
#pragma unroll
      for (int b = 0; b < 4; b++) bfr[b] = ldfrag2(&Bs[wn * 64 + b * 16 + lr][0], o1, o2);
#pragma unroll
      for (int a = 0; a < 4; a++)
#pragma unroll
        for (int b = 0; b < 4; b++)
          acc[a][b] = __builtin_amdgcn_mfma_f32_16x16x32_bf16(af[a], bfr[b], acc[a][b], 0, 0, 0);
    }
    __syncthreads();
  }
#pragma unroll
  for (int a = 0; a < 4; a++) {
#pragma unroll
    for (int b = 0; b < 4; b++) {
      const int c = n0 + wn * 64 + b * 16 + lr;
      float bb = (MODE == 1) ? bias[c] : 0.f;
#pragma unroll
      for (int j = 0; j < 4; j++) {
        const int r = m0 + wm * 64 + a * 16 + lg * 4 + j;
        if (MODE == 0)
          Cb[(size_t)r * N + c] = f2b(acc[a][b][j]);
        else
          Cf[(size_t)r * N + c] = acc[a][b][j] + bb;
      }
    }
  }
}

// ---------------- V -> Vt  (per (b,h): [S,64] -> [64,S]) ----------------
__global__ void k_vtrans(const u16* __restrict__ V, u16* __restrict__ Vt) {
  const int bh = blockIdx.y, b = bh >> 4, h = bh & 15;
  const int t0 = blockIdx.x * 64;
  __shared__ u16 tile[64][72];
  const int t = threadIdx.x;
#pragma unroll
  for (int p = 0; p < 2; p++) {
    int c = p * 256 + t;
    int row = c >> 3, off = (c & 7) * 8;
    *(s16x8*)&tile[row][off] =
        *(const s16x8*)&V[(size_t)(b * SEQ + t0 + row) * DM + h * HD + off];
  }
  __syncthreads();
#pragma unroll
  for (int p = 0; p < 2; p++) {
    int c = p * 256 + t;
    int vd = c >> 3, off = (c & 7) * 8;
    union { u16 a[8]; s16x8 v; } u;
#pragma unroll
    for (int i = 0; i < 8; i++) u.a[i] = tile[off + i][vd];
    *(s16x8*)&Vt[(size_t)(bh * HD + vd) * SEQ + t0 + off] = u.v;
  }
}

// ---------------- flash attention (swapped QK^T, lane-local softmax) ----------------
// grid (SEQ/128, B*H), 256 thr = 4 waves; wave w owns q rows [q0+32w, q0+32w+32)
__global__ __launch_bounds__(256) void k_attn(const u16* __restrict__ Q, const u16* __restrict__ K,
                                              const u16* __restrict__ Vt, u16* __restrict__ O) {
  __shared__ u16 KS[2][64][64];
  __shared__ u16 VS[2][64][64];   // V^T tile: [vd][key], pre-swizzled
  const int bh = blockIdx.y, b = bh >> 4, h = bh & 15;
  const int q0 = blockIdx.x * 128;
  const int t = threadIdx.x, w = t >> 6, lane = t & 63, lr = lane & 15, lg = lane >> 4;
  const int l8 = lane >> 3;
  const int scol = (((lane & 7) ^ l8) << 3);
  const int xsw = (lr & 7) << 3;
  const float sc = 0.125f;  // 1/sqrt(64)

  // Q fragments (B-operand; lane holds Q[q=lr][d=kk*32+4lg+i, +16]) for 2 q-blocks
  bf16x8 qf[2][2];
#pragma unroll
  for (int qb = 0; qb < 2; qb++) {
    const u16* qp = Q + (size_t)(b * SEQ + q0 + w * 32 + qb * 16 + lr) * DM + h * HD + 4 * lg;
    qf[qb][0] = ldfrag(qp);
    qf[qb][1] = ldfrag(qp + 32);
  }

  float m[2] = {-3e38f, -3e38f}, l[2] = {0.f, 0.f};
  const f32x4 z4 = {0.f, 0.f, 0.f, 0.f};
  f32x4 o[2][4];
#pragma unroll
  for (int qb = 0; qb < 2; qb++)
#pragma unroll
    for (int v = 0; v < 4; v++) o[qb][v] = z4;

  // stage one K/V tile (64x64) into buffer `buf`; wave handles 2 segments each
#define STAGE(buf, kv)                                                                  \
  {                                                                                     \
    _Pragma("unroll") for (int s2 = 0; s2 < 2; s2++) {                                  \
      const int seg = w * 2 + s2;                                                       \
      const int row = seg * 8 + l8;                                                     \
      GLOAD_LDS(K + (size_t)(b * SEQ + (kv) + row) * DM + h * HD + scol,                \
                &KS[buf][seg * 8][0]);                                                  \
      GLOAD_LDS(Vt + (size_t)(bh * HD + row) * SEQ + (kv) + scol, &VS[buf][seg * 8][0]);\
    }                                                                                   \
  }

  STAGE(0, 0);
  __syncthreads();

  for (int it = 0; it < SEQ / 64; it++) {
    const int cur = it & 1;
    if (it < SEQ / 64 - 1) STAGE(cur ^ 1, (it + 1) * 64);

    // S^T = K Q^T : lane holds S[key=16n+4lg+j][q=lr]
    f32x4 s[2][4];
#pragma unroll
    for (int qb = 0; qb < 2; qb++)
#pragma unroll
      for (int n = 0; n < 4; n++) s[qb][n] = z4;
#pragma unroll
    for (int kk = 0; kk < 2; kk++) {
      const int e = kk * 32 + 4 * lg;
      const int o1 = e ^ xsw, o2 = (e + 16) ^ xsw;
      bf16x8 kf[4];
#pragma unroll
      for (int n = 0; n < 4; n++) kf[n] = ldfrag2(&KS[cur][16 * n + lr][0], o1, o2);
#pragma unroll
      for (int qb = 0; qb < 2; qb++)
#pragma unroll
        for (int n = 0; n < 4; n++)
          s[qb][n] = __builtin_amdgcn_mfma_f32_16x16x32_bf16(kf[n], qf[qb][kk], s[qb][n], 0, 0, 0);
    }

    // lane-local online softmax (all 16 scores for q=lr are in-register)
    bf16x8 pf[2][2];
#pragma unroll
    for (int qb = 0; qb < 2; qb++) {
      f32x4 t4 = vmax4(vmax4(s[qb][0], s[qb][1]), vmax4(s[qb][2], s[qb][3]));
      float mx = fmaxf(fmaxf(t4[0], t4[1]), fmaxf(t4[2], t4[3]));
      mx = fmaxf(mx, __shfl_xor(mx, 16));
      mx = fmaxf(mx, __shfl_xor(mx, 32));
      const float mn = fmaxf(m[qb], mx);
      const float al = __expf((m[qb] - mn) * sc);
      m[qb] = mn;
      union { u16 a[16]; bf16x8 v[2]; } pk;
      float r = 0.f;
#pragma unroll
      for (int n = 0; n < 4; n++)
#pragma unroll
        for (int j = 0; j < 4; j++) {
          float p = __expf((s[qb][n][j] - mn) * sc);
          r += p;
          pk.a[n * 4 + j] = f2b(p);
        }
      r += __shfl_xor(r, 16);
      r += __shfl_xor(r, 32);
      l[qb] = l[qb] * al + r;
      pf[qb][0] = pk.v[0];
      pf[qb][1] = pk.v[1];
      // broadcast rescale factor to O-rows (O row = q = 4lg+j; al lives at lane lr=q)
      float alr[4];
#pragma unroll
      for (int j = 0; j < 4; j++) alr[j] = __shfl(al, 4 * lg + j);
#pragma unroll
      for (int v = 0; v < 4; v++)
#pragma unroll
        for (int j = 0; j < 4; j++) o[qb][v][j] *= alr[j];
    }

    // O += P V : A = P (in-register!), B = V^T tile
#pragma unroll
    for (int kc = 0; kc < 2; kc++) {
      const int e = kc * 32 + 4 * lg;
      const int o1 = e ^ xsw, o2 = (e + 16) ^ xsw;
      bf16x8 vf[4];
#pragma unroll
      for (int v = 0; v < 4; v++) vf[v] = ldfrag2(&VS[cur][16 * v + lr][0], o1, o2);
#pragma unroll
      for (int qb = 0; qb < 2; qb++)
#pragma unroll
        for (int v = 0; v < 4; v++)
          o[qb][v] = __builtin_amdgcn_mfma_f32_16x16x32_bf16(pf[qb][kc], vf[v], o[qb][v], 0, 0, 0);
    }
    __syncthreads();
  }

#pragma unroll
  for (int qb = 0; qb < 2; qb++) {
    float linv[4];
#pragma unroll
    for (int j = 0; j < 4; j++) linv[j] = 1.0f / __shfl(l[qb], 4 * lg + j);
#pragma unroll
    for (int v = 0; v < 4; v++)
#pragma unroll
      for (int j = 0; j < 4; j++)
        O[(size_t)(b * SEQ + q0 + w * 32 + qb * 16 + 4 * lg + j) * DM + h * HD + v * 16 + lr] =
            f2b(o[qb][v][j] * linv[j]);
  }
#undef STAGE
}

// ---------------- launch ----------------
extern "C" void kernel_launch(void* const* d_in, const int* in_sizes, int n_in,
                              void* d_out, int out_size, void* d_ws, size_t ws_size,
                              hipStream_t stream) {
  const float* x  = (const float*)d_in[0];
  const float* Wq = (const float*)d_in[1];
  const float* Wk = (const float*)d_in[2];
  const float* Wv = (const float*)d_in[3];
  const float* Wo = (const float*)d_in[4];
  const float* bo = (const float*)d_in[5];
  float* out = (float*)d_out;

  char* ws = (char*)d_ws;
  const size_t MB = 1 << 20;
  u16* xb  = (u16*)(ws + 0 * MB);
  u16* WqT = (u16*)(ws + 8 * MB);
  u16* WkT = (u16*)(ws + 10 * MB);
  u16* WvT = (u16*)(ws + 12 * MB);
  u16* WoT = (u16*)(ws + 14 * MB);
  u16* Qb  = (u16*)(ws + 16 * MB);
  u16* Kb  = (u16*)(ws + 24 * MB);
  u16* Vb  = (u16*)(ws + 32 * MB);
  u16* Vtb = (u16*)(ws + 40 * MB);
  u16* Ob  = (u16*)(ws + 48 * MB);

  k_cvt<<<dim3(NTOK * DM / 1024), 256, 0, stream>>>(x, xb);
  k_wtrans<<<dim3(32, 32, 4), 256, 0, stream>>>(Wq, Wk, Wv, Wo, WqT, WkT, WvT, WoT);
  k_gemm<0><<<dim3(8, 32, 3), 256, 0, stream>>>(xb, WqT, WkT, WvT, Qb, Kb, Vb, nullptr, nullptr);
  k_vtrans<<<dim3(32, 32), 256, 0, stream>>>(Vb, Vtb);
  k_attn<<<dim3(16, 32), 256, 0, stream>>>(Qb, Kb, Vtb, Ob);
  k_gemm<1><<<dim3(8, 32, 1), 256, 0, stream>>>(Ob, WoT, nullptr, nullptr, nullptr, nullptr,
                                                nullptr, out, bo);
}